// Round 3
// baseline (21590.984 us; speedup 1.0000x reference)
//
#include <hip/hip_runtime.h>
#include <math.h>

#define S_LEN 4096
#define NTAG 20
#define TAG_STOP 19
#define NEGV -10000.0f
#define NWGD 32            // worker blocks per LSTM direction (4 waves each, 4 units/wave)
#define NCAND 512          // candidate blocks launched for the LSTM kernel

typedef unsigned int uint4v __attribute__((ext_vector_type(4)));

// ---------------- workspace layout (bytes) ----------------
// [0,256)          uint claim[64]
// [4096,20480)     ull h_loc[2][2][512]   (dir, parity, unit) packed {seq32|h32}  - XCD-local L2 path
// [32768,49152)    ull h_rem[2][2][512]   - L3/agent path (fallback)
// [65536, +64MB)   float pre[4096][4096]
// then             float hs[2][4096][512]
// then             float feats[4096][20]
// then             u8 bptr[4096*20]

__global__ void init_ws(unsigned int* claim, unsigned long long* hloc, unsigned long long* hrem) {
    int i = blockIdx.x * 256 + threadIdx.x;
    if (i < 64) claim[i] = 0u;
    if (i < 2048) { hloc[i] = 0ull; hrem[i] = 0ull; }
}

__device__ __forceinline__ float sigm(float x) { return 1.0f / (1.0f + expf(-x)); }

// ---------------- kernel A: embed gather + input GEMM (fp32) ----------------
__launch_bounds__(256)
__global__ void pre_gemm(const int* __restrict__ sent, const float* __restrict__ embed,
                         const float* __restrict__ wf, const float* __restrict__ wb,
                         const float* __restrict__ bihf, const float* __restrict__ bhhf,
                         const float* __restrict__ bihb, const float* __restrict__ bhhb,
                         float* __restrict__ pre)
{
    __shared__ float As[16][68];
    __shared__ float Bs[16][136];
    __shared__ int   srow[64];
    const int tid = threadIdx.x;
    const int bm = blockIdx.x & 63;
    const int bn = blockIdx.x >> 6;
    const int pos0 = bm * 64, row0 = bn * 128;
    if (tid < 64) srow[tid] = sent[pos0 + tid];
    __syncthreads();

    const int tx = tid & 15, ty = tid >> 4;
    float acc[4][8];
    #pragma unroll
    for (int m = 0; m < 4; ++m)
        #pragma unroll
        for (int n = 0; n < 8; ++n) acc[m][n] = 0.f;

    for (int kt = 0; kt < 1024; kt += 16) {
        {
            int m = tid >> 2, kc = (tid & 3) * 4;
            const float* src = embed + (size_t)srow[m] * 1024 + kt + kc;
            float4 v = *(const float4*)src;
            As[kc+0][m] = v.x; As[kc+1][m] = v.y; As[kc+2][m] = v.z; As[kc+3][m] = v.w;
        }
        #pragma unroll
        for (int it = 0; it < 2; ++it) {
            int n = (tid >> 2) + it * 64;
            int kc = (tid & 3) * 4;
            int grow = row0 + n;
            const float* wsrc = (grow < 2048) ? (wf + (size_t)grow * 1024)
                                              : (wb + (size_t)(grow - 2048) * 1024);
            float4 v = *(const float4*)(wsrc + kt + kc);
            Bs[kc+0][n] = v.x; Bs[kc+1][n] = v.y; Bs[kc+2][n] = v.z; Bs[kc+3][n] = v.w;
        }
        __syncthreads();
        #pragma unroll
        for (int kk = 0; kk < 16; ++kk) {
            float a[4], b[8];
            float4 av = *(const float4*)&As[kk][ty * 4];
            a[0] = av.x; a[1] = av.y; a[2] = av.z; a[3] = av.w;
            float4 bv0 = *(const float4*)&Bs[kk][tx * 8];
            float4 bv1 = *(const float4*)&Bs[kk][tx * 8 + 4];
            b[0]=bv0.x; b[1]=bv0.y; b[2]=bv0.z; b[3]=bv0.w;
            b[4]=bv1.x; b[5]=bv1.y; b[6]=bv1.z; b[7]=bv1.w;
            #pragma unroll
            for (int m = 0; m < 4; ++m)
                #pragma unroll
                for (int n = 0; n < 8; ++n) acc[m][n] += a[m] * b[n];
        }
        __syncthreads();
    }
    #pragma unroll
    for (int m = 0; m < 4; ++m) {
        int pos = pos0 + ty * 4 + m;
        #pragma unroll
        for (int n = 0; n < 8; ++n) {
            int grow = row0 + tx * 8 + n;
            float bias = (grow < 2048) ? (bihf[grow] + bhhf[grow])
                                       : (bihb[grow - 2048] + bhhb[grow - 2048]);
            pre[(size_t)pos * 4096 + grow] = acc[m][n] + bias;
        }
    }
}

// ---------------- LSTM comm primitives ----------------
__device__ __forceinline__ void sc0_load4(const unsigned long long* p,
                                          uint4v& a, uint4v& b, uint4v& c, uint4v& d) {
    asm volatile(
        "global_load_dwordx4 %0, %4, off sc0\n\t"
        "global_load_dwordx4 %1, %4, off offset:16 sc0\n\t"
        "global_load_dwordx4 %2, %4, off offset:32 sc0\n\t"
        "global_load_dwordx4 %3, %4, off offset:48 sc0\n\t"
        "s_waitcnt vmcnt(0)"
        : "=&v"(a), "=&v"(b), "=&v"(c), "=&v"(d)
        : "v"(p)
        : "memory");
}
__device__ __forceinline__ uint4v sc0_load1(const unsigned long long* p) {
    uint4v a;
    asm volatile("global_load_dwordx4 %0, %1, off sc0\n\ts_waitcnt vmcnt(0)"
                 : "=&v"(a) : "v"(p) : "memory");
    return a;
}

// Poll one 16B chunk (2 units). hi dwords (.y,.w) are seq tags; lo dwords are h bits.
// Fast path: sc0 loads from the XCD-local L2 copy. Fallback (and adaptive remote
// mode via rmask bit): agent-scope loads of the L3 copy. Each 8B half is an
// independent atom, so mixing sources per-half is safe.
__device__ __forceinline__ uint4v poll_chunk(const unsigned long long* lp,
                                             unsigned long long* rp,
                                             unsigned int expect, uint4v cur,
                                             int& rmask, int bit) {
    if (cur.y >= expect && cur.w >= expect) return cur;
    if (rmask & bit) {
        while (cur.y < expect || cur.w < expect) {
            unsigned long long r0 = __hip_atomic_load(rp,     __ATOMIC_RELAXED, __HIP_MEMORY_SCOPE_AGENT);
            unsigned long long r1 = __hip_atomic_load(rp + 1, __ATOMIC_RELAXED, __HIP_MEMORY_SCOPE_AGENT);
            if ((unsigned int)(r0 >> 32) >= expect) { cur.x = (unsigned int)r0; cur.y = (unsigned int)(r0 >> 32); }
            if ((unsigned int)(r1 >> 32) >= expect) { cur.z = (unsigned int)r1; cur.w = (unsigned int)(r1 >> 32); }
        }
        return cur;
    }
    int spins = 0;
    while (cur.y < expect || cur.w < expect) {
        if ((++spins & 15) == 0) {
            unsigned long long r0 = __hip_atomic_load(rp,     __ATOMIC_RELAXED, __HIP_MEMORY_SCOPE_AGENT);
            unsigned long long r1 = __hip_atomic_load(rp + 1, __ATOMIC_RELAXED, __HIP_MEMORY_SCOPE_AGENT);
            bool got = false;
            if ((unsigned int)(r0 >> 32) >= expect && cur.y < expect) { cur.x = (unsigned int)r0; cur.y = (unsigned int)(r0 >> 32); got = true; }
            if ((unsigned int)(r1 >> 32) >= expect && cur.w < expect) { cur.z = (unsigned int)r1; cur.w = (unsigned int)(r1 >> 32); got = true; }
            if (got) rmask |= bit;   // remote beat local: use remote directly next steps
        } else {
            uint4v nl = sc0_load1(lp);
            if (nl.y >= expect && cur.y < expect) { cur.x = nl.x; cur.y = nl.y; }
            if (nl.w >= expect && cur.w < expect) { cur.z = nl.z; cur.w = nl.w; }
        }
    }
    return cur;
}

// ---------------- one LSTM step (PARW = publish parity, compile-time) ----------------
template<int PARW>
__device__ __forceinline__ void lstm_step(
    int s, int dir, int u, int wv, int lane, int ks, int lroff,
    const float* __restrict__ pre, const float* __restrict__ h0,
    float* __restrict__ hs,
    unsigned long long* hloc_d, unsigned long long* hrem_d,
    float (&h_lds)[4][2][576],
    const float (&wr0)[32], const float (&wr1)[32],
    const float (&wr2)[32], const float (&wr3)[32],
    float (&pf)[4], float (&pft)[4], float& c_reg, int& rmask)
{
    const int pos = dir ? (S_LEN - 1 - s) : s;
    constexpr int PARR = PARW ^ 1;

    // ---- stage h_{s-1}: each lane owns units lane*8..lane*8+7 of its wave's copy ----
    if (s == 0) {
        const float* h0p = h0 + dir * 512 + lane * 8;
        float4 a = *(const float4*)h0p;
        float4 b = *(const float4*)(h0p + 4);
        *(float4*)&h_lds[wv][PARR][lroff]     = a;
        *(float4*)&h_lds[wv][PARR][lroff + 4] = b;
    } else {
        const unsigned int expect = (unsigned int)s;
        const unsigned long long* lp = hloc_d + PARR * 512 + lane * 8;
        unsigned long long*       rp = hrem_d + PARR * 512 + lane * 8;
        uint4v q0, q1, q2, q3;
        sc0_load4(lp, q0, q1, q2, q3);
        q0 = poll_chunk(lp + 0, rp + 0, expect, q0, rmask, 1);
        q1 = poll_chunk(lp + 2, rp + 2, expect, q1, rmask, 2);
        q2 = poll_chunk(lp + 4, rp + 4, expect, q2, rmask, 4);
        q3 = poll_chunk(lp + 6, rp + 6, expect, q3, rmask, 8);
        float4 f0 = make_float4(__uint_as_float(q0.x), __uint_as_float(q0.z),
                                __uint_as_float(q1.x), __uint_as_float(q1.z));
        float4 f1 = make_float4(__uint_as_float(q2.x), __uint_as_float(q2.z),
                                __uint_as_float(q3.x), __uint_as_float(q3.z));
        *(float4*)&h_lds[wv][PARR][lroff]     = f0;
        *(float4*)&h_lds[wv][PARR][lroff + 4] = f1;
    }
    asm volatile("s_waitcnt lgkmcnt(0)" ::: "memory");
    __builtin_amdgcn_sched_barrier(0);

    // ---- issue pre prefetch for step s+2 (gate lanes); drained by NEXT body's poll ----
    if (ks == 0 && s + 2 < S_LEN) {
        const int pp = dir ? (S_LEN - 3 - s) : (s + 2);
        const float* pb = pre + (size_t)pp * 4096 + dir * 2048 + u;
        pft[0] = pb[0]; pft[1] = pb[512]; pft[2] = pb[1024]; pft[3] = pb[1536];
    }

    // ---- matvec: 4 gate rows x 32 k per lane, weights in VGPRs ----
    float a0 = 0.f, a1 = 0.f, a2 = 0.f, a3 = 0.f;
    const float* hp = &h_lds[wv][PARR][ks * 36];
    #pragma unroll
    for (int q = 0; q < 8; ++q) {
        float4 h4 = ((const float4*)hp)[q];
        a0 += wr0[q*4+0]*h4.x + wr0[q*4+1]*h4.y + wr0[q*4+2]*h4.z + wr0[q*4+3]*h4.w;
        a1 += wr1[q*4+0]*h4.x + wr1[q*4+1]*h4.y + wr1[q*4+2]*h4.z + wr1[q*4+3]*h4.w;
        a2 += wr2[q*4+0]*h4.x + wr2[q*4+1]*h4.y + wr2[q*4+2]*h4.z + wr2[q*4+3]*h4.w;
        a3 += wr3[q*4+0]*h4.x + wr3[q*4+1]*h4.y + wr3[q*4+2]*h4.z + wr3[q*4+3]*h4.w;
    }
    // ---- 16-lane butterfly reduce over k-slices ----
    a0 += __shfl_xor(a0, 1); a0 += __shfl_xor(a0, 2); a0 += __shfl_xor(a0, 4); a0 += __shfl_xor(a0, 8);
    a1 += __shfl_xor(a1, 1); a1 += __shfl_xor(a1, 2); a1 += __shfl_xor(a1, 4); a1 += __shfl_xor(a1, 8);
    a2 += __shfl_xor(a2, 1); a2 += __shfl_xor(a2, 2); a2 += __shfl_xor(a2, 4); a2 += __shfl_xor(a2, 8);
    a3 += __shfl_xor(a3, 1); a3 += __shfl_xor(a3, 2); a3 += __shfl_xor(a3, 4); a3 += __shfl_xor(a3, 8);

    // ---- gates + publish (lane ks==0 of each rg-group: 1 unit) ----
    if (ks == 0) {
        float gi = a0 + pf[0], gf = a1 + pf[1], gg = a2 + pf[2], go = a3 + pf[3];
        float cn = sigm(gf) * c_reg + sigm(gi) * tanhf(gg);
        float hN = sigm(go) * tanhf(cn);
        c_reg = cn;
        hs[((size_t)dir * S_LEN + pos) * 512 + u] = hN;
        unsigned long long uv = ((unsigned long long)(unsigned int)(s + 1) << 32)
                              | (unsigned long long)__float_as_uint(hN);
        __hip_atomic_store(hloc_d + PARW * 512 + u, uv, __ATOMIC_RELAXED, __HIP_MEMORY_SCOPE_WORKGROUP);
        __hip_atomic_store(hrem_d + PARW * 512 + u, uv, __ATOMIC_RELAXED, __HIP_MEMORY_SCOPE_AGENT);
        pf[0] = pft[0]; pf[1] = pft[1]; pf[2] = pft[2]; pf[3] = pft[3];
    }
}

// ---------------- kernel B: bidirectional LSTM, wave-autonomous, XCD-placed ----------------
// NCAND candidate blocks; claim protocol picks NWGD workers/dir, preferring XCD0
// (dir0) / XCD1 (dir1) via HW_REG_XCC_ID. Workers: 4 waves x 4 units each; no
// __syncthreads in the step loop (each wave stages its own h copy; seq tags make
// the 2-parity overwrite safe per-wave). Weights 128 f32/lane in VGPRs.
__launch_bounds__(256, 1)
__global__ void lstm_kernel(const float* __restrict__ pre,
                            const float* __restrict__ w_hh_f, const float* __restrict__ w_hh_b,
                            const float* __restrict__ h0, const float* __restrict__ c0,
                            float* __restrict__ hs,
                            unsigned long long* __restrict__ h_loc,
                            unsigned long long* __restrict__ h_rem,
                            unsigned int* __restrict__ claim)
{
    __shared__ int s_sel;
    __shared__ float h_lds[4][2][576];

    if (threadIdx.x == 0) {
        int xcd;
        asm volatile("s_getreg_b32 %0, hwreg(HW_REG_XCC_ID)" : "=s"(xcd));
        xcd &= 15;
        int sel = -1;
        if (xcd == 0) {
            unsigned idx = atomicAdd(&claim[0], 1u);
            if (idx < NWGD) sel = (int)idx;                 // dir0
        } else if (xcd == 1) {
            unsigned idx = atomicAdd(&claim[1], 1u);
            if (idx < NWGD) sel = 64 + (int)idx;            // dir1
        }
        if (sel < 0) {
            long long t0 = clock64();
            while (true) {
                unsigned c0v = __hip_atomic_load(&claim[0], __ATOMIC_RELAXED, __HIP_MEMORY_SCOPE_AGENT);
                unsigned c1v = __hip_atomic_load(&claim[1], __ATOMIC_RELAXED, __HIP_MEMORY_SCOPE_AGENT);
                if (c0v >= NWGD && c1v >= NWGD) break;
                if (clock64() - t0 > 1500000) {             // ~0.6 ms: fallback claim
                    if (c0v < NWGD) { unsigned idx = atomicAdd(&claim[0], 1u); if (idx < NWGD) { sel = (int)idx; break; } }
                    if (c1v < NWGD) { unsigned idx = atomicAdd(&claim[1], 1u); if (idx < NWGD) { sel = 64 + (int)idx; break; } }
                    break;
                }
                __builtin_amdgcn_s_sleep(8);
            }
        }
        s_sel = sel;
    }
    __syncthreads();
    const int sel = s_sel;
    if (sel < 0) return;
    const int dir = sel >> 6;
    const int wg  = sel & 63;

    const int tid  = threadIdx.x;
    const int wv   = tid >> 6;
    const int lane = tid & 63;
    const int rg   = lane >> 4;
    const int ks   = lane & 15;
    const int u    = wg * 16 + wv * 4 + rg;            // this lane-group's unit
    const int lroff = lane * 8 + ((lane >> 2) << 2);   // padded LDS offset of unit lane*8
    const float* w_hh = dir ? w_hh_b : w_hh_f;

    // ---- load weights into VGPRs: 4 gate rows (g*512+u) x 32 k (ks slice) ----
    float wr0[32], wr1[32], wr2[32], wr3[32];
    {
        const float* wbase = w_hh + (size_t)u * 512 + ks * 32;
        #pragma unroll
        for (int q = 0; q < 8; ++q) {
            float4 v0 = *(const float4*)(wbase + 0 * 262144 + q * 4);
            wr0[q*4+0] = v0.x; wr0[q*4+1] = v0.y; wr0[q*4+2] = v0.z; wr0[q*4+3] = v0.w;
            float4 v1 = *(const float4*)(wbase + 1 * 262144 + q * 4);
            wr1[q*4+0] = v1.x; wr1[q*4+1] = v1.y; wr1[q*4+2] = v1.z; wr1[q*4+3] = v1.w;
            float4 v2 = *(const float4*)(wbase + 2 * 262144 + q * 4);
            wr2[q*4+0] = v2.x; wr2[q*4+1] = v2.y; wr2[q*4+2] = v2.z; wr2[q*4+3] = v2.w;
            float4 v3 = *(const float4*)(wbase + 3 * 262144 + q * 4);
            wr3[q*4+0] = v3.x; wr3[q*4+1] = v3.y; wr3[q*4+2] = v3.z; wr3[q*4+3] = v3.w;
        }
    }

    float c_reg = 0.f;
    float pfA[4] = {0,0,0,0}, pfB[4] = {0,0,0,0};
    float pftA[4] = {0,0,0,0}, pftB[4] = {0,0,0,0};
    if (ks == 0) {
        c_reg = c0[dir * 512 + u];
        const int p0 = dir ? (S_LEN - 1) : 0;
        const int p1 = dir ? (S_LEN - 2) : 1;
        const float* pb0 = pre + (size_t)p0 * 4096 + dir * 2048 + u;
        const float* pb1 = pre + (size_t)p1 * 4096 + dir * 2048 + u;
        pfA[0] = pb0[0]; pfA[1] = pb0[512]; pfA[2] = pb0[1024]; pfA[3] = pb0[1536];
        pfB[0] = pb1[0]; pfB[1] = pb1[512]; pfB[2] = pb1[1024]; pfB[3] = pb1[1536];
    }

    unsigned long long* hloc_d = h_loc + dir * 1024;
    unsigned long long* hrem_d = h_rem + dir * 1024;
    int rmask = 0;

    for (int s = 0; s < S_LEN; s += 2) {
        lstm_step<0>(s,     dir, u, wv, lane, ks, lroff, pre, h0, hs, hloc_d, hrem_d,
                     h_lds, wr0, wr1, wr2, wr3, pfA, pftA, c_reg, rmask);
        lstm_step<1>(s + 1, dir, u, wv, lane, ks, lroff, pre, h0, hs, hloc_d, hrem_d,
                     h_lds, wr0, wr1, wr2, wr3, pfB, pftB, c_reg, rmask);
    }
}

// ---------------- kernel C: feats = concat(hf,hb) @ w_out^T + b_out ----------------
__launch_bounds__(256)
__global__ void feats_kernel(const float* __restrict__ hs, const float* __restrict__ w_out,
                             const float* __restrict__ b_out, float* __restrict__ feats)
{
    const int pos = blockIdx.x;
    const int tid = threadIdx.x;
    __shared__ float hbuf[1024];
    __shared__ float red[160];
    {
        const float* hf = hs + (size_t)pos * 512;
        const float* hb = hs + ((size_t)S_LEN + pos) * 512;
        if (tid < 128) *(float4*)&hbuf[tid * 4]           = *(const float4*)&hf[tid * 4];
        else           *(float4*)&hbuf[512 + (tid-128)*4] = *(const float4*)&hb[(tid - 128) * 4];
    }
    __syncthreads();
    if (tid < 160) {
        int tag = tid >> 3, part = tid & 7;
        const float* wrow = w_out + (size_t)tag * 1024 + part * 128;
        const float* hrow = hbuf + part * 128;
        float sum = 0.f;
        #pragma unroll
        for (int q = 0; q < 32; ++q) {
            float4 a = ((const float4*)hrow)[q];
            float4 b = ((const float4*)wrow)[q];
            sum += a.x*b.x + a.y*b.y + a.z*b.z + a.w*b.w;
        }
        red[tid] = sum;
    }
    __syncthreads();
    if (tid < NTAG) {
        float sum = b_out[tid];
        #pragma unroll
        for (int p = 0; p < 8; ++p) sum += red[tid * 8 + p];
        feats[(size_t)pos * NTAG + tid] = sum;
    }
}

// ---------------- kernel D: Viterbi forward + chunked backtrace ----------------
__launch_bounds__(256)
__global__ void viterbi_kernel(const float* __restrict__ feats, const float* __restrict__ trans,
                               unsigned char* __restrict__ bptr, float* __restrict__ out)
{
    __shared__ float feat_lds[64 * NTAG];
    __shared__ int sh_best;
    __shared__ unsigned char Mmap[8][NTAG];
    __shared__ unsigned char entry_s[8];
    const int tid = threadIdx.x;

    if (tid < 64) {
        const int lane = tid;
        const int i = (lane < NTAG) ? lane : (NTAG - 1);
        float trow[NTAG];
        #pragma unroll
        for (int j = 0; j < NTAG; ++j) trow[j] = trans[i * NTAG + j];
        float fv[NTAG];
        #pragma unroll
        for (int j = 0; j < NTAG; ++j) fv[j] = (j == 18) ? 0.f : NEGV;

        for (int blk = 0; blk < 64; ++blk) {
            #pragma unroll
            for (int q = 0; q < 20; ++q)
                feat_lds[q * 64 + lane] = feats[blk * 1280 + q * 64 + lane];
            for (int ss = 0; ss < 64; ++ss) {
                int s = blk * 64 + ss;
                float best = fv[0] + trow[0];
                int bj = 0;
                #pragma unroll
                for (int j = 1; j < NTAG; ++j) {
                    float cand = fv[j] + trow[j];
                    if (cand > best) { best = cand; bj = j; }
                }
                float fnew = best + feat_lds[ss * NTAG + i];
                if (lane < NTAG) bptr[s * NTAG + lane] = (unsigned char)bj;
                #pragma unroll
                for (int j = 0; j < NTAG; ++j) fv[j] = __shfl(fnew, j);
            }
        }
        if (lane == 0) {
            float best = -1e30f; int bt = 0;
            for (int j = 0; j < NTAG; ++j) {
                float t2 = fv[j] + trans[TAG_STOP * NTAG + j];
                if (t2 > best) { best = t2; bt = j; }
            }
            out[0] = best;
            sh_best = bt;
        }
    }
    __syncthreads();
    if (tid < 160) {
        int c = tid / NTAG, e = tid % NTAG;
        int tag = e;
        for (int t = (c + 1) * 512 - 1; t >= c * 512; --t) tag = bptr[t * NTAG + tag];
        Mmap[c][e] = (unsigned char)tag;
    }
    __syncthreads();
    if (tid == 0) {
        int e = sh_best;
        entry_s[7] = (unsigned char)e;
        for (int c = 7; c >= 1; --c) { e = Mmap[c][e]; entry_s[c - 1] = (unsigned char)e; }
    }
    __syncthreads();
    if (tid < 8) {
        int c = tid;
        int tag = entry_s[c];
        out[1 + (c + 1) * 512 - 1] = (float)tag;
        for (int t = (c + 1) * 512 - 1; t > c * 512; --t) {
            tag = bptr[t * NTAG + tag];
            out[1 + t - 1] = (float)tag;
        }
    }
}

extern "C" void kernel_launch(void* const* d_in, const int* in_sizes, int n_in,
                              void* d_out, int out_size, void* d_ws, size_t ws_size,
                              hipStream_t stream) {
    (void)in_sizes; (void)n_in; (void)out_size; (void)ws_size;
    const int*   sent  = (const int*)d_in[0];
    const float* embed = (const float*)d_in[1];
    const float* wihf  = (const float*)d_in[2];
    const float* whhf  = (const float*)d_in[3];
    const float* bihf  = (const float*)d_in[4];
    const float* bhhf  = (const float*)d_in[5];
    const float* wihb  = (const float*)d_in[6];
    const float* whhb  = (const float*)d_in[7];
    const float* bihb  = (const float*)d_in[8];
    const float* bhhb  = (const float*)d_in[9];
    const float* wout  = (const float*)d_in[10];
    const float* bout  = (const float*)d_in[11];
    const float* trans = (const float*)d_in[12];
    const float* h0    = (const float*)d_in[13];
    const float* c0    = (const float*)d_in[14];

    char* ws = (char*)d_ws;
    unsigned int* claim        = (unsigned int*)ws;
    unsigned long long* h_loc  = (unsigned long long*)(ws + 4096);
    unsigned long long* h_rem  = (unsigned long long*)(ws + 32768);
    float* pre   = (float*)(ws + 65536);
    float* hs    = (float*)(ws + 65536 + (size_t)4096 * 4096 * 4);
    float* feats = (float*)(ws + 65536 + (size_t)4096 * 4096 * 4 + (size_t)2 * 4096 * 512 * 4);
    unsigned char* bptr = (unsigned char*)(feats + (size_t)S_LEN * NTAG);
    float* out = (float*)d_out;

    hipLaunchKernelGGL(init_ws, dim3(8), dim3(256), 0, stream, claim, h_loc, h_rem);
    hipLaunchKernelGGL(pre_gemm, dim3(2048), dim3(256), 0, stream,
                       sent, embed, wihf, wihb, bihf, bhhf, bihb, bhhb, pre);
    hipLaunchKernelGGL(lstm_kernel, dim3(NCAND), dim3(256), 0, stream,
                       pre, whhf, whhb, h0, c0, hs, h_loc, h_rem, claim);
    hipLaunchKernelGGL(feats_kernel, dim3(S_LEN), dim3(256), 0, stream,
                       hs, wout, bout, feats);
    hipLaunchKernelGGL(viterbi_kernel, dim3(1), dim3(256), 0, stream,
                       feats, trans, bptr, out);
}

// Round 4
// 10695.771 us; speedup vs baseline: 2.0186x; 2.0186x over previous
//
#include <hip/hip_runtime.h>
#include <math.h>

#define S_LEN 4096
#define NTAG 20
#define TAG_STOP 19
#define NEGV -10000.0f
#define NWG 16   // workgroups per LSTM direction

// ---------------- workspace layout (bytes) ----------------
// [4096,20480)     ull h_pub[2][2][512]   (dir, parity, unit) packed {seq32|h32}
// [65536, +64MB)   float pre[4096][4096]  (pos, row; rows 0..2047 fwd, 2048..4095 bwd)
// then             float hs[2][4096][512]
// then             float feats[4096][20]
// then             u8 bptr[4096*20]

__global__ void init_ws(unsigned long long* hpub) {
    int i = blockIdx.x * 256 + threadIdx.x;
    if (i < 2048) hpub[i] = 0ull;
}

__device__ __forceinline__ float sigm(float x) { return 1.0f / (1.0f + expf(-x)); }

// ---------------- kernel A: embed gather + input GEMM (fp32) ----------------
__launch_bounds__(256)
__global__ void pre_gemm(const int* __restrict__ sent, const float* __restrict__ embed,
                         const float* __restrict__ wf, const float* __restrict__ wb,
                         const float* __restrict__ bihf, const float* __restrict__ bhhf,
                         const float* __restrict__ bihb, const float* __restrict__ bhhb,
                         float* __restrict__ pre)
{
    __shared__ float As[16][68];
    __shared__ float Bs[16][136];
    __shared__ int   srow[64];
    const int tid = threadIdx.x;
    const int bm = blockIdx.x & 63;
    const int bn = blockIdx.x >> 6;
    const int pos0 = bm * 64, row0 = bn * 128;
    if (tid < 64) srow[tid] = sent[pos0 + tid];
    __syncthreads();

    const int tx = tid & 15, ty = tid >> 4;
    float acc[4][8];
    #pragma unroll
    for (int m = 0; m < 4; ++m)
        #pragma unroll
        for (int n = 0; n < 8; ++n) acc[m][n] = 0.f;

    for (int kt = 0; kt < 1024; kt += 16) {
        {
            int m = tid >> 2, kc = (tid & 3) * 4;
            const float* src = embed + (size_t)srow[m] * 1024 + kt + kc;
            float4 v = *(const float4*)src;
            As[kc+0][m] = v.x; As[kc+1][m] = v.y; As[kc+2][m] = v.z; As[kc+3][m] = v.w;
        }
        #pragma unroll
        for (int it = 0; it < 2; ++it) {
            int n = (tid >> 2) + it * 64;
            int kc = (tid & 3) * 4;
            int grow = row0 + n;
            const float* wsrc = (grow < 2048) ? (wf + (size_t)grow * 1024)
                                              : (wb + (size_t)(grow - 2048) * 1024);
            float4 v = *(const float4*)(wsrc + kt + kc);
            Bs[kc+0][n] = v.x; Bs[kc+1][n] = v.y; Bs[kc+2][n] = v.z; Bs[kc+3][n] = v.w;
        }
        __syncthreads();
        #pragma unroll
        for (int kk = 0; kk < 16; ++kk) {
            float a[4], b[8];
            float4 av = *(const float4*)&As[kk][ty * 4];
            a[0] = av.x; a[1] = av.y; a[2] = av.z; a[3] = av.w;
            float4 bv0 = *(const float4*)&Bs[kk][tx * 8];
            float4 bv1 = *(const float4*)&Bs[kk][tx * 8 + 4];
            b[0]=bv0.x; b[1]=bv0.y; b[2]=bv0.z; b[3]=bv0.w;
            b[4]=bv1.x; b[5]=bv1.y; b[6]=bv1.z; b[7]=bv1.w;
            #pragma unroll
            for (int m = 0; m < 4; ++m)
                #pragma unroll
                for (int n = 0; n < 8; ++n) acc[m][n] += a[m] * b[n];
        }
        __syncthreads();
    }
    #pragma unroll
    for (int m = 0; m < 4; ++m) {
        int pos = pos0 + ty * 4 + m;
        #pragma unroll
        for (int n = 0; n < 8; ++n) {
            int grow = row0 + tx * 8 + n;
            float bias = (grow < 2048) ? (bihf[grow] + bhhf[grow])
                                       : (bihb[grow - 2048] + bhhb[grow - 2048]);
            pre[(size_t)pos * 4096 + grow] = acc[m][n] + bias;
        }
    }
}

// ---------------- one LSTM step (P = s&1, compile-time) ----------------
// stage(s) fills buf[P] with h_{s-1}; publish(s) -> pub[P^1] with tag s+1 and
// own-unit LDS write into buf[P^1] (next step's read buffer).
template<int P>
__device__ __forceinline__ void lstm_step(
    int s, int dir, int wg, int j, int ks, int su, bool own, int sidx, bool gate,
    const float* __restrict__ pre, const float* __restrict__ h0,
    float* __restrict__ hs, unsigned long long* pub,
    float (&buf)[2][576],
    const float (&wr0)[32], const float (&wr1)[32],
    const float (&wr2)[32], const float (&wr3)[32],
    float (&pf)[4], float& c_reg)
{
    // ---- stage h_{s-1} into buf[P] (one 8B poll per thread; own units skipped) ----
    if (s == 0) {
        buf[0][sidx] = h0[dir * 512 + su];
    } else if (!own) {
        const unsigned int expect = (unsigned int)s;
        unsigned long long u = __hip_atomic_load(&pub[P * 512 + su],
                                                 __ATOMIC_RELAXED, __HIP_MEMORY_SCOPE_AGENT);
        while ((unsigned int)(u >> 32) < expect)
            u = __hip_atomic_load(&pub[P * 512 + su],
                                  __ATOMIC_RELAXED, __HIP_MEMORY_SCOPE_AGENT);
        buf[P][sidx] = __uint_as_float((unsigned int)u);
    }
    __syncthreads();   // the only barrier per step

    // ---- matvec: 4 gate rows x 32 k per lane, weights in VGPRs ----
    float a0 = 0.f, a1 = 0.f, a2 = 0.f, a3 = 0.f;
    const float* hp = &buf[P][ks * 36];
    #pragma unroll
    for (int q = 0; q < 8; ++q) {
        float4 h4 = ((const float4*)hp)[q];
        a0 += wr0[q*4+0]*h4.x + wr0[q*4+1]*h4.y + wr0[q*4+2]*h4.z + wr0[q*4+3]*h4.w;
        a1 += wr1[q*4+0]*h4.x + wr1[q*4+1]*h4.y + wr1[q*4+2]*h4.z + wr1[q*4+3]*h4.w;
        a2 += wr2[q*4+0]*h4.x + wr2[q*4+1]*h4.y + wr2[q*4+2]*h4.z + wr2[q*4+3]*h4.w;
        a3 += wr3[q*4+0]*h4.x + wr3[q*4+1]*h4.y + wr3[q*4+2]*h4.z + wr3[q*4+3]*h4.w;
    }
    // ---- 16-lane butterfly reduce over k-slices ----
    a0 += __shfl_xor(a0, 1); a0 += __shfl_xor(a0, 2); a0 += __shfl_xor(a0, 4); a0 += __shfl_xor(a0, 8);
    a1 += __shfl_xor(a1, 1); a1 += __shfl_xor(a1, 2); a1 += __shfl_xor(a1, 4); a1 += __shfl_xor(a1, 8);
    a2 += __shfl_xor(a2, 1); a2 += __shfl_xor(a2, 2); a2 += __shfl_xor(a2, 4); a2 += __shfl_xor(a2, 8);
    a3 += __shfl_xor(a3, 1); a3 += __shfl_xor(a3, 2); a3 += __shfl_xor(a3, 4); a3 += __shfl_xor(a3, 8);

    // ---- gates + publish (lane ks==0 of each 16-group: 1 unit) ----
    if (gate) {
        float gi = a0 + pf[0], gf = a1 + pf[1], gg = a2 + pf[2], go = a3 + pf[3];
        float cn = sigm(gf) * c_reg + sigm(gi) * tanhf(gg);
        float hN = sigm(go) * tanhf(cn);
        c_reg = cn;
        const int pos = dir ? (S_LEN - 1 - s) : s;
        hs[((size_t)dir * S_LEN + pos) * 512 + j] = hN;
        buf[P ^ 1][j + 4 * wg] = hN;                    // own-unit fast path (next parity)
        unsigned long long uv = ((unsigned long long)(unsigned int)(s + 1) << 32)
                              | (unsigned long long)__float_as_uint(hN);
        __hip_atomic_store(&pub[(P ^ 1) * 512 + j], uv,
                           __ATOMIC_RELAXED, __HIP_MEMORY_SCOPE_AGENT);
        // ---- distance-2 pre prefetch for step s+2 ----
        if (s + 2 < S_LEN) {
            const int pp = dir ? (S_LEN - 3 - s) : (s + 2);
            const float* pb = pre + (size_t)pp * 4096 + dir * 2048 + j;
            pf[0] = pb[0]; pf[1] = pb[512]; pf[2] = pb[1024]; pf[3] = pb[1536];
        }
    }
}

// ---------------- kernel B: bidirectional LSTM ----------------
// 32 blocks x 512 threads (8 waves, 2/SIMD). blocks 0..15 = fwd, 16..31 = bwd.
// Block owns 32 units (128 gate rows). Lane-group (16 lanes) computes 1 unit:
// 4 gate rows x 32 k each -> 128 weight floats/lane, genuinely VGPR-resident
// under __launch_bounds__(512,2)'s 256-reg cap. Each thread stages exactly ONE
// foreign unit per step via a single 8B data-is-flag agent atomic poll.
__launch_bounds__(512, 2)
__global__ void lstm_kernel(const float* __restrict__ pre,
                            const float* __restrict__ w_hh_f, const float* __restrict__ w_hh_b,
                            const float* __restrict__ h0, const float* __restrict__ c0,
                            float* __restrict__ hs, unsigned long long* __restrict__ h_pub)
{
    const int dir  = blockIdx.x >> 4;
    const int wg   = blockIdx.x & 15;
    const int tid  = threadIdx.x;
    const int wv   = tid >> 6;
    const int lane = tid & 63;
    const int rg   = lane >> 4;
    const int ks   = lane & 15;
    const int j    = wg * 32 + wv * 4 + rg;        // this lane-group's global unit
    const float* w_hh = dir ? w_hh_b : w_hh_f;

    __shared__ float buf[2][576];   // double-buffered h, pad 4 per 32

    // ---- weights: 4 gate rows (g*512+j) x 32 k (ks slice), 128 f32 in VGPRs ----
    float wr0[32], wr1[32], wr2[32], wr3[32];
    {
        const float* wbase = w_hh + (size_t)j * 512 + ks * 32;
        #pragma unroll
        for (int q = 0; q < 8; ++q) {
            float4 v0 = *(const float4*)(wbase + 0 * 262144 + q * 4);
            wr0[q*4+0] = v0.x; wr0[q*4+1] = v0.y; wr0[q*4+2] = v0.z; wr0[q*4+3] = v0.w;
            float4 v1 = *(const float4*)(wbase + 1 * 262144 + q * 4);
            wr1[q*4+0] = v1.x; wr1[q*4+1] = v1.y; wr1[q*4+2] = v1.z; wr1[q*4+3] = v1.w;
            float4 v2 = *(const float4*)(wbase + 2 * 262144 + q * 4);
            wr2[q*4+0] = v2.x; wr2[q*4+1] = v2.y; wr2[q*4+2] = v2.z; wr2[q*4+3] = v2.w;
            float4 v3 = *(const float4*)(wbase + 3 * 262144 + q * 4);
            wr3[q*4+0] = v3.x; wr3[q*4+1] = v3.y; wr3[q*4+2] = v3.z; wr3[q*4+3] = v3.w;
        }
    }

    const bool gate = (ks == 0);
    float c_reg = 0.f;
    float pfA[4] = {0,0,0,0}, pfB[4] = {0,0,0,0};
    if (gate) {
        c_reg = c0[dir * 512 + j];
        const int p0 = dir ? (S_LEN - 1) : 0;
        const int p1 = dir ? (S_LEN - 2) : 1;
        const float* b0 = pre + (size_t)p0 * 4096 + dir * 2048 + j;
        const float* b1 = pre + (size_t)p1 * 4096 + dir * 2048 + j;
        pfA[0] = b0[0]; pfA[1] = b0[512]; pfA[2] = b0[1024]; pfA[3] = b0[1536];
        pfB[0] = b1[0]; pfB[1] = b1[512]; pfB[2] = b1[1024]; pfB[3] = b1[1536];
    }

    const int  su   = tid;                       // unit staged by this thread
    const bool own  = ((su >> 5) == wg);         // own units come via LDS fast path
    const int  sidx = su + ((su >> 5) << 2);     // padded LDS index
    unsigned long long* pub = h_pub + dir * 1024;

    for (int s = 0; s < S_LEN; s += 2) {
        lstm_step<0>(s,     dir, wg, j, ks, su, own, sidx, gate,
                     pre, h0, hs, pub, buf, wr0, wr1, wr2, wr3, pfA, c_reg);
        lstm_step<1>(s + 1, dir, wg, j, ks, su, own, sidx, gate,
                     pre, h0, hs, pub, buf, wr0, wr1, wr2, wr3, pfB, c_reg);
    }
}

// ---------------- kernel C: feats = concat(hf,hb) @ w_out^T + b_out ----------------
__launch_bounds__(256)
__global__ void feats_kernel(const float* __restrict__ hs, const float* __restrict__ w_out,
                             const float* __restrict__ b_out, float* __restrict__ feats)
{
    const int pos = blockIdx.x;
    const int tid = threadIdx.x;
    __shared__ float hbuf[1024];
    __shared__ float red[160];
    {
        const float* hf = hs + (size_t)pos * 512;
        const float* hb = hs + ((size_t)S_LEN + pos) * 512;
        if (tid < 128) *(float4*)&hbuf[tid * 4]           = *(const float4*)&hf[tid * 4];
        else           *(float4*)&hbuf[512 + (tid-128)*4] = *(const float4*)&hb[(tid - 128) * 4];
    }
    __syncthreads();
    if (tid < 160) {
        int tag = tid >> 3, part = tid & 7;
        const float* wrow = w_out + (size_t)tag * 1024 + part * 128;
        const float* hrow = hbuf + part * 128;
        float sum = 0.f;
        #pragma unroll
        for (int q = 0; q < 32; ++q) {
            float4 a = ((const float4*)hrow)[q];
            float4 b = ((const float4*)wrow)[q];
            sum += a.x*b.x + a.y*b.y + a.z*b.z + a.w*b.w;
        }
        red[tid] = sum;
    }
    __syncthreads();
    if (tid < NTAG) {
        float sum = b_out[tid];
        #pragma unroll
        for (int p = 0; p < 8; ++p) sum += red[tid * 8 + p];
        feats[(size_t)pos * NTAG + tid] = sum;
    }
}

// ---------------- kernel D: Viterbi forward + chunked backtrace ----------------
__launch_bounds__(256)
__global__ void viterbi_kernel(const float* __restrict__ feats, const float* __restrict__ trans,
                               unsigned char* __restrict__ bptr, float* __restrict__ out)
{
    __shared__ float feat_lds[64 * NTAG];
    __shared__ int sh_best;
    __shared__ unsigned char Mmap[8][NTAG];
    __shared__ unsigned char entry_s[8];
    const int tid = threadIdx.x;

    if (tid < 64) {
        const int lane = tid;
        const int i = (lane < NTAG) ? lane : (NTAG - 1);
        float trow[NTAG];
        #pragma unroll
        for (int jj = 0; jj < NTAG; ++jj) trow[jj] = trans[i * NTAG + jj];
        float fv[NTAG];
        #pragma unroll
        for (int jj = 0; jj < NTAG; ++jj) fv[jj] = (jj == 18) ? 0.f : NEGV;

        for (int blk = 0; blk < 64; ++blk) {
            #pragma unroll
            for (int q = 0; q < 20; ++q)
                feat_lds[q * 64 + lane] = feats[blk * 1280 + q * 64 + lane];
            for (int ss = 0; ss < 64; ++ss) {
                int s = blk * 64 + ss;
                float best = fv[0] + trow[0];
                int bj = 0;
                #pragma unroll
                for (int jj = 1; jj < NTAG; ++jj) {
                    float cand = fv[jj] + trow[jj];
                    if (cand > best) { best = cand; bj = jj; }   // strict >: first-max tie rule
                }
                float fnew = best + feat_lds[ss * NTAG + i];
                if (lane < NTAG) bptr[s * NTAG + lane] = (unsigned char)bj;
                #pragma unroll
                for (int jj = 0; jj < NTAG; ++jj) fv[jj] = __shfl(fnew, jj);
            }
        }
        if (lane == 0) {
            float best = -1e30f; int bt = 0;
            for (int jj = 0; jj < NTAG; ++jj) {
                float t2 = fv[jj] + trans[TAG_STOP * NTAG + jj];
                if (t2 > best) { best = t2; bt = jj; }
            }
            out[0] = best;
            sh_best = bt;
        }
    }
    __syncthreads();
    if (tid < 160) {
        int c = tid / NTAG, e = tid % NTAG;
        int tag = e;
        for (int t = (c + 1) * 512 - 1; t >= c * 512; --t) tag = bptr[t * NTAG + tag];
        Mmap[c][e] = (unsigned char)tag;
    }
    __syncthreads();
    if (tid == 0) {
        int e = sh_best;
        entry_s[7] = (unsigned char)e;
        for (int c = 7; c >= 1; --c) { e = Mmap[c][e]; entry_s[c - 1] = (unsigned char)e; }
    }
    __syncthreads();
    if (tid < 8) {
        int c = tid;
        int tag = entry_s[c];
        out[1 + (c + 1) * 512 - 1] = (float)tag;
        for (int t = (c + 1) * 512 - 1; t > c * 512; --t) {
            tag = bptr[t * NTAG + tag];
            out[1 + t - 1] = (float)tag;
        }
    }
}

extern "C" void kernel_launch(void* const* d_in, const int* in_sizes, int n_in,
                              void* d_out, int out_size, void* d_ws, size_t ws_size,
                              hipStream_t stream) {
    (void)in_sizes; (void)n_in; (void)out_size; (void)ws_size;
    const int*   sent  = (const int*)d_in[0];
    const float* embed = (const float*)d_in[1];
    const float* wihf  = (const float*)d_in[2];
    const float* whhf  = (const float*)d_in[3];
    const float* bihf  = (const float*)d_in[4];
    const float* bhhf  = (const float*)d_in[5];
    const float* wihb  = (const float*)d_in[6];
    const float* whhb  = (const float*)d_in[7];
    const float* bihb  = (const float*)d_in[8];
    const float* bhhb  = (const float*)d_in[9];
    const float* wout  = (const float*)d_in[10];
    const float* bout  = (const float*)d_in[11];
    const float* trans = (const float*)d_in[12];
    const float* h0    = (const float*)d_in[13];
    const float* c0    = (const float*)d_in[14];

    char* ws = (char*)d_ws;
    unsigned long long* h_pub = (unsigned long long*)(ws + 4096);   // 16 KB
    float* pre   = (float*)(ws + 65536);
    float* hs    = (float*)(ws + 65536 + (size_t)4096 * 4096 * 4);
    float* feats = (float*)(ws + 65536 + (size_t)4096 * 4096 * 4 + (size_t)2 * 4096 * 512 * 4);
    unsigned char* bptr = (unsigned char*)(feats + (size_t)S_LEN * NTAG);
    float* out = (float*)d_out;

    hipLaunchKernelGGL(init_ws, dim3(8), dim3(256), 0, stream, h_pub);
    hipLaunchKernelGGL(pre_gemm, dim3(2048), dim3(256), 0, stream,
                       sent, embed, wihf, wihb, bihf, bhhf, bihb, bhhb, pre);
    hipLaunchKernelGGL(lstm_kernel, dim3(32), dim3(512), 0, stream,
                       pre, whhf, whhb, h0, c0, hs, h_pub);
    hipLaunchKernelGGL(feats_kernel, dim3(S_LEN), dim3(256), 0, stream,
                       hs, wout, bout, feats);
    hipLaunchKernelGGL(viterbi_kernel, dim3(1), dim3(256), 0, stream,
                       feats, trans, bptr, out);
}